// Round 4
// baseline (299.495 us; speedup 1.0000x reference)
//
#include <hip/hip_runtime.h>

// HyperNet fused forward, v7.1 — mega-fusion (compile fix of v7: DOT4 macro
// parameter `w` collided with the `.w` member token and expanded to `a.wb`).
//   prep:  fused[97][1024] = [enc_w2;pol_w3;pol_b3] @ comb_w (+comb_b), and w1T = pol_w1^T.
//   mega:  per 16-row block: phase A computes h1[16][64], h2[16][32] into LDS sH[16][96];
//          phase B = proven R0 logits loop (j0=t*4, 24 k4, w reg-dbuf) + epilogue.
// R2 post-mortem: readlane broadcast REGRESSED (90us, +VALU work; uniform-address LDS
//   broadcast was already ~free). Reverted to sH-broadcast GEMM; killed the h1h2 global
//   roundtrip (24MB) and one dispatch by fusing h-compute into the logits kernel.

#define N_CLIENTS 16384
#define P 1024
#define IN_DIM 512

#define FMA4(acc, a, w0, w1, w2, w3)                                  \
  acc.x = fmaf(a.x, w0.x, acc.x); acc.y = fmaf(a.x, w0.y, acc.y);     \
  acc.z = fmaf(a.x, w0.z, acc.z); acc.w = fmaf(a.x, w0.w, acc.w);     \
  acc.x = fmaf(a.y, w1.x, acc.x); acc.y = fmaf(a.y, w1.y, acc.y);     \
  acc.z = fmaf(a.y, w1.z, acc.z); acc.w = fmaf(a.y, w1.w, acc.w);     \
  acc.x = fmaf(a.z, w2.x, acc.x); acc.y = fmaf(a.z, w2.y, acc.y);     \
  acc.z = fmaf(a.z, w2.z, acc.z); acc.w = fmaf(a.z, w2.w, acc.w);     \
  acc.x = fmaf(a.w, w3.x, acc.x); acc.y = fmaf(a.w, w3.y, acc.y);     \
  acc.z = fmaf(a.w, w3.z, acc.z); acc.w = fmaf(a.w, w3.w, acc.w);

#define DOT4(sAcc, vA, vW)                                                  \
  sAcc = fmaf(vA.x, vW.x, sAcc); sAcc = fmaf(vA.y, vW.y, sAcc);             \
  sAcc = fmaf(vA.z, vW.z, sAcc); sAcc = fmaf(vA.w, vW.w, sAcc);

// ---------------------------------------------------------------------------
// prep (840 blocks x 128):
//   [0,832)   fused = folded weights @ comb_w, k-split x8 (k=128), atomicAdd
//             (fused pre-zeroed by memset). by 13 x jc 8 x kz 8.
//   [832,840) w1T[32][1024] = pol_w1^T (LDS-bounced transpose, 128 k-rows/block)
// ---------------------------------------------------------------------------
__global__ __launch_bounds__(128) void prep(
    const float* __restrict__ enc_w2,    // [64][1024]
    const float* __restrict__ pol_w3,    // [32][1024]
    const float* __restrict__ pol_b3,    // [1024]
    const float* __restrict__ comb_w,    // [2048][1024]
    const float* __restrict__ comb_b,    // [1024]
    const float* __restrict__ pol_w1,    // [1024][32]
    float* __restrict__ fused,           // [97][1024] (pre-zeroed)
    float* __restrict__ w1T)             // [32][1024]
{
    const int t = threadIdx.x;
    const int bid = blockIdx.x;

    if (bid < 832) {
        const int jc = bid & 7;
        const int rest = bid >> 3;        // [0,104)
        const int by = rest % 13;
        const int kz = rest / 13;         // [0,8)
        const int j = jc * 128 + t;

        if (by < 12) {
            const float* wsrc = (by < 8) ? (enc_w2 + by * 8 * 1024)
                                         : (pol_w3 + (by - 8) * 8 * 1024);
            const int kbase   = (by < 8) ? 0 : 1024;
            const int outbase = (by < 8) ? by * 8 : 64 + (by - 8) * 8;
            const float* cw = comb_w + ((size_t)kbase + kz * 128) * 1024 + j;
            float acc[8];
            #pragma unroll
            for (int r = 0; r < 8; ++r) acc[r] = 0.f;
            #pragma unroll 4
            for (int k = 0; k < 128; ++k) {
                const float c = cw[(size_t)k * 1024];
                #pragma unroll
                for (int r = 0; r < 8; ++r)
                    acc[r] = fmaf(wsrc[r * 1024 + kz * 128 + k], c, acc[r]); // uniform -> s_load
            }
            #pragma unroll
            for (int r = 0; r < 8; ++r)
                atomicAdd(&fused[(outbase + r) * 1024 + j], acc[r]);
        } else {
            const float* cw = comb_w + ((size_t)1024 + kz * 128) * 1024 + j;
            float acc = 0.f;
            #pragma unroll 4
            for (int k = 0; k < 128; ++k)
                acc = fmaf(pol_b3[kz * 128 + k], cw[(size_t)k * 1024], acc);
            atomicAdd(&fused[96 * 1024 + j], acc + (kz == 0 ? comb_b[j] : 0.f));
        }
    } else {
        // ---- pol_w1 transpose: this block handles k-rows [k0, k0+128)
        __shared__ __attribute__((aligned(16))) float sT2[128 * 36];
        const int k0 = (bid - 832) * 128;
        #pragma unroll
        for (int i = 0; i < 8; ++i) {
            const int idx = i * 128 + t;            // f4 index 0..1023
            const int row = idx >> 3, seg = idx & 7;
            *(float4*)(sT2 + row * 36 + seg * 4) =
                *(const float4*)(pol_w1 + (k0 + row) * 32 + seg * 4);
        }
        __syncthreads();
        const int c = t >> 2, q = t & 3;
        #pragma unroll
        for (int i = 0; i < 8; ++i) {
            const int kk = q * 32 + i * 4;
            float4 v;
            v.x = sT2[(kk + 0) * 36 + c];
            v.y = sT2[(kk + 1) * 36 + c];
            v.z = sT2[(kk + 2) * 36 + c];
            v.w = sT2[(kk + 3) * 36 + c];
            *(float4*)(w1T + c * 1024 + k0 + kk) = v;
        }
    }
}

// ---------------------------------------------------------------------------
// mega (1024 blocks x 256): 16 rows each.
//   A1: h1 = relu(enc @ enc_w1), thread = 1 row (rg=t>>4) x 4 cols (c0=(t&15)*4),
//       K=512 in 8 tiles of 64, reg-prefetch staging.
//   A2: h2l1 = mean @ pol_w1 via w1T, thread = 1 row x cols {c4, c4+16}, K=1024 in
//       16 tiles of 64; parity-split scalar accs for ILP. Then layer2 (K=32) in LDS.
//   B:  logits from sH broadcast (uniform-address b128 = free) + fused from L2,
//       w reg-dbuf; sigmoid/sample/logprob epilogue. Full row -> no atomics.
// ---------------------------------------------------------------------------
__global__ __launch_bounds__(256, 4) void mega(
    const float* __restrict__ encoding,  // [N][512]
    const float* __restrict__ mean,      // [N][1024]
    const float* __restrict__ enc_w1,    // [512][64]
    const float* __restrict__ pol_b1,    // [32]
    const float* __restrict__ pol_w2,    // [32][32]
    const float* __restrict__ pol_b2,    // [32]
    const float* __restrict__ fused,     // [97][1024]
    const float* __restrict__ w1T,       // [32][1024]
    const float* __restrict__ eps,       // [N][1024]
    float* __restrict__ out_sample,      // [N][1024]
    float* __restrict__ out_logprob,     // [N]
    float* __restrict__ out_entropy)     // [N]
{
    __shared__ __attribute__((aligned(16))) float sW[64 * 64];  // 16KB: h1-W / w1T[32][68] / pol_w2[32][36]
    __shared__ __attribute__((aligned(16))) float sA[16 * 68];  // A tiles; reused as t1[16][36]
    __shared__ __attribute__((aligned(16))) float sH[16 * 96];  // 6KB h outputs
    __shared__ float s_red[16][4];

    const int t = threadIdx.x;
    const long r0 = (long)blockIdx.x * 16;
    const int rg = t >> 4;        // row 0..15
    const int c4 = t & 15;
    const int c0 = c4 * 4;

    // ================= phase A1: h1 (16x64, K=512) =================
    {
        const float* aSrc = encoding + (r0 + rg) * IN_DIM + c0;
        const float* wSrc = enc_w1 + rg * 64 + c0;
        float4 aR  = *(const float4*)(aSrc);
        float4 wR0 = *(const float4*)(wSrc);
        float4 wR1 = *(const float4*)(wSrc + 1024);
        float4 wR2 = *(const float4*)(wSrc + 2048);
        float4 wR3 = *(const float4*)(wSrc + 3072);
        float4 h1a = {0.f, 0.f, 0.f, 0.f};

        for (int kt = 0; kt < 8; ++kt) {
            __syncthreads();
            *(float4*)(sA + rg * 68 + c0) = aR;
            *(float4*)(sW + (rg +  0) * 64 + c0) = wR0;
            *(float4*)(sW + (rg + 16) * 64 + c0) = wR1;
            *(float4*)(sW + (rg + 32) * 64 + c0) = wR2;
            *(float4*)(sW + (rg + 48) * 64 + c0) = wR3;
            __syncthreads();
            if (kt < 7) {
                aR  = *(const float4*)(aSrc + (kt + 1) * 64);
                wR0 = *(const float4*)(wSrc + (kt + 1) * 4096);
                wR1 = *(const float4*)(wSrc + 1024 + (kt + 1) * 4096);
                wR2 = *(const float4*)(wSrc + 2048 + (kt + 1) * 4096);
                wR3 = *(const float4*)(wSrc + 3072 + (kt + 1) * 4096);
            }
            #pragma unroll
            for (int k4 = 0; k4 < 16; ++k4) {
                const float4 a  = *(const float4*)(sA + rg * 68 + k4 * 4);
                const float4 w0 = *(const float4*)(sW + (k4 * 4 + 0) * 64 + c0);
                const float4 w1 = *(const float4*)(sW + (k4 * 4 + 1) * 64 + c0);
                const float4 w2 = *(const float4*)(sW + (k4 * 4 + 2) * 64 + c0);
                const float4 w3 = *(const float4*)(sW + (k4 * 4 + 3) * 64 + c0);
                FMA4(h1a, a, w0, w1, w2, w3);
            }
        }
        float4 o;
        o.x = fmaxf(h1a.x, 0.f); o.y = fmaxf(h1a.y, 0.f);
        o.z = fmaxf(h1a.z, 0.f); o.w = fmaxf(h1a.w, 0.f);
        *(float4*)(sH + rg * 96 + c0) = o;     // distinct region; next barrier protects sA/sW
    }

    // ================= phase A2: h2 layer1 (16x32, K=1024) =================
    float s0, s1;
    {
        const float* mSrc  = mean + (r0 + rg) * P + c0;
        const float* wtSrc = w1T + rg * 1024 + c0;      // rows rg, rg+16 of w1T
        float4 aR  = *(const float4*)(mSrc);
        float4 wR0 = *(const float4*)(wtSrc);
        float4 wR1 = *(const float4*)(wtSrc + 16 * 1024);
        float s0e = 0.f, s0o = 0.f, s1e = 0.f, s1o = 0.f;

        for (int kt = 0; kt < 16; ++kt) {
            __syncthreads();
            *(float4*)(sA + rg * 68 + c0) = aR;
            *(float4*)(sW + (rg +  0) * 68 + c0) = wR0;
            *(float4*)(sW + (rg + 16) * 68 + c0) = wR1;
            __syncthreads();
            if (kt < 15) {
                aR  = *(const float4*)(mSrc + (kt + 1) * 64);
                wR0 = *(const float4*)(wtSrc + (kt + 1) * 64);
                wR1 = *(const float4*)(wtSrc + 16 * 1024 + (kt + 1) * 64);
            }
            #pragma unroll
            for (int k4 = 0; k4 < 16; ++k4) {
                const float4 a  = *(const float4*)(sA + rg * 68 + k4 * 4);
                const float4 wa = *(const float4*)(sW + c4 * 68 + k4 * 4);
                const float4 wb = *(const float4*)(sW + (c4 + 16) * 68 + k4 * 4);
                if (k4 & 1) { DOT4(s0o, a, wa); DOT4(s1o, a, wb); }
                else        { DOT4(s0e, a, wa); DOT4(s1e, a, wb); }
            }
        }
        s0 = s0e + s0o; s1 = s1e + s1o;
    }

    // ================= phase A3: h2 layer2 (K=32) =================
    {
        __syncthreads();
        const float t1a = fmaxf(s0 + pol_b1[c4], 0.f);
        const float t1b = fmaxf(s1 + pol_b1[c4 + 16], 0.f);
        sA[rg * 36 + c4] = t1a;
        sA[rg * 36 + c4 + 16] = t1b;
        *(float4*)(sW + (t >> 3) * 36 + (t & 7) * 4) =
            *(const float4*)(pol_w2 + (t >> 3) * 32 + (t & 7) * 4);
        __syncthreads();
        float d0 = 0.f, d1 = 0.f;
        #pragma unroll
        for (int k4 = 0; k4 < 8; ++k4) {
            const float4 a = *(const float4*)(sA + rg * 36 + k4 * 4);
            d0 = fmaf(a.x, sW[(k4 * 4 + 0) * 36 + c4], d0);
            d0 = fmaf(a.y, sW[(k4 * 4 + 1) * 36 + c4], d0);
            d0 = fmaf(a.z, sW[(k4 * 4 + 2) * 36 + c4], d0);
            d0 = fmaf(a.w, sW[(k4 * 4 + 3) * 36 + c4], d0);
            d1 = fmaf(a.x, sW[(k4 * 4 + 0) * 36 + c4 + 16], d1);
            d1 = fmaf(a.y, sW[(k4 * 4 + 1) * 36 + c4 + 16], d1);
            d1 = fmaf(a.z, sW[(k4 * 4 + 2) * 36 + c4 + 16], d1);
            d1 = fmaf(a.w, sW[(k4 * 4 + 3) * 36 + c4 + 16], d1);
        }
        sH[rg * 96 + 64 + c4]      = fmaxf(d0 + pol_b2[c4], 0.f);
        sH[rg * 96 + 64 + c4 + 16] = fmaxf(d1 + pol_b2[c4 + 16], 0.f);
        __syncthreads();
    }

    // ================= phase B: logits + epilogue (R0-proven) =================
    const int j0 = t * 4;
    const float* fj = fused + j0;

    float4 acc[16];
    {
        const float4 b = *(const float4*)(fj + 96 * 1024);
        #pragma unroll
        for (int r = 0; r < 16; ++r) acc[r] = b;
    }

    float4 wc0 = *(const float4*)(fj);
    float4 wc1 = *(const float4*)(fj + 1024);
    float4 wc2 = *(const float4*)(fj + 2048);
    float4 wc3 = *(const float4*)(fj + 3072);

    for (int k4 = 0; k4 < 24; ++k4) {
        const int kn = (k4 < 23) ? (k4 + 1) * 4 : 92;   // last-iter dummy prefetch
        const float* fn = fj + (size_t)kn * 1024;
        const float4 wn0 = *(const float4*)(fn);
        const float4 wn1 = *(const float4*)(fn + 1024);
        const float4 wn2 = *(const float4*)(fn + 2048);
        const float4 wn3 = *(const float4*)(fn + 3072);
        #pragma unroll
        for (int r = 0; r < 16; ++r) {
            const float4 h = *(const float4*)(sH + r * 96 + k4 * 4);  // uniform broadcast
            FMA4(acc[r], h, wc0, wc1, wc2, wc3);
        }
        wc0 = wn0; wc1 = wn1; wc2 = wn2; wc3 = wn3;
    }

    float sq[16];
    const float* ep = eps + r0 * P + j0;
    float* sp = out_sample + r0 * P + j0;
    #pragma unroll
    for (int r = 0; r < 16; ++r) {
        const float m0 = 1.f / (1.f + __expf(-acc[r].x));
        const float m1 = 1.f / (1.f + __expf(-acc[r].y));
        const float m2 = 1.f / (1.f + __expf(-acc[r].z));
        const float m3 = 1.f / (1.f + __expf(-acc[r].w));
        const float4 e = *(const float4*)(ep + r * P);
        const float v0 = fminf(fmaxf(fmaf(0.22360679774997896f, e.x, m0), 0.f), 1.f);
        const float v1 = fminf(fmaxf(fmaf(0.22360679774997896f, e.y, m1), 0.f), 1.f);
        const float v2 = fminf(fmaxf(fmaf(0.22360679774997896f, e.z, m2), 0.f), 1.f);
        const float v3 = fminf(fmaxf(fmaf(0.22360679774997896f, e.w, m3), 0.f), 1.f);
        *(float4*)(sp + r * P) = make_float4(v0, v1, v2, v3);
        const float d0 = v0 - m0, d1 = v1 - m1, d2 = v2 - m2, d3 = v3 - m3;
        sq[r] = fmaf(d0, d0, fmaf(d1, d1, fmaf(d2, d2, d3 * d3)));
    }
    #pragma unroll
    for (int r = 0; r < 16; ++r) {
        float v = sq[r];
        v += __shfl_xor(v, 1);
        v += __shfl_xor(v, 2);
        v += __shfl_xor(v, 4);
        v += __shfl_xor(v, 8);
        v += __shfl_xor(v, 16);
        v += __shfl_xor(v, 32);
        if ((t & 63) == 0) s_red[r][t >> 6] = v;
    }
    __syncthreads();
    if (t < 16) {
        const float v = s_red[t][0] + s_red[t][1] + s_red[t][2] + s_red[t][3];
        out_logprob[r0 + t] = fmaf(-10.f, v, 592.8218660580586f);
        out_entropy[r0 + t] = -80.82186605805855f;
    }
}

extern "C" void kernel_launch(void* const* d_in, const int* in_sizes, int n_in,
                              void* d_out, int out_size, void* d_ws, size_t ws_size,
                              hipStream_t stream) {
    const float* encoding = (const float*)d_in[0];
    const float* mean     = (const float*)d_in[1];
    const float* enc_w1   = (const float*)d_in[2];
    const float* enc_w2   = (const float*)d_in[3];
    const float* pol_w1   = (const float*)d_in[4];
    const float* pol_b1   = (const float*)d_in[5];
    const float* pol_w2   = (const float*)d_in[6];
    const float* pol_b2   = (const float*)d_in[7];
    const float* pol_w3   = (const float*)d_in[8];
    const float* pol_b3   = (const float*)d_in[9];
    const float* comb_w   = (const float*)d_in[10];
    const float* comb_b   = (const float*)d_in[11];
    const float* eps      = (const float*)d_in[12];

    float* fused = (float*)d_ws;                 // 97*1024 floats
    float* w1T   = fused + 97 * 1024;            // 32*1024 floats
    float* out_sample  = (float*)d_out;
    float* out_logprob = out_sample + (size_t)N_CLIENTS * P;
    float* out_entropy = out_logprob + N_CLIENTS;

    (void)hipMemsetAsync(fused, 0, 97 * 1024 * sizeof(float), stream);

    prep<<<840, 128, 0, stream>>>(enc_w2, pol_w3, pol_b3, comb_w, comb_b,
                                  pol_w1, fused, w1T);

    mega<<<N_CLIENTS / 16, 256, 0, stream>>>(encoding, mean, enc_w1, pol_b1,
                                             pol_w2, pol_b2, fused, w1T, eps,
                                             out_sample, out_logprob, out_entropy);
}

// Round 6
// 272.483 us; speedup vs baseline: 1.0991x; 1.0991x over previous
//
#include <hip/hip_runtime.h>

// HyperNet fused forward, v9 (resubmit — R5 bench was an infra failure).
//   logits = h1 @ (enc_w2 @ comb_top) + h2 @ (pol_w3 @ comb_bot) + (pol_b3 @ comb_bot + comb_b)
//   h1 = relu(enc @ enc_w1) [N,64],  h2 = relu(relu(mean@pol_w1+b1)@pol_w2+b2) [N,32]
//
// R4 post-mortem: mega-fusion regressed (144us): 16-row blocks re-staged full weight
//   panels per block -> ~256MB L2 weight traffic at 6.5 F/B (L2-BW-bound). Reverted to
//   the v4 split stage1 (proven <=75us).
// logits theory: v4's 77us was LDS-issue-bound (per k4: 768 LDS-pipe cyc/CU vs 512 FMA
//   cyc/SIMD for the sH broadcast). v9 reads h via WAVE-UNIFORM global loads -> compiler
//   emits s_load_dwordx4 (SMEM pipe, SGPR operand in the FMA) -> LDS + VALU both relieved.
//   8-row blocks (2048) double residency vs v4's 1024.

#define N_CLIENTS 16384
#define P 1024
#define IN_DIM 512
#define SPAD 36   // LDS row stride for A tiles

#define FMA4(acc, a, w0, w1, w2, w3)                                  \
  acc.x = fmaf(a.x, w0.x, acc.x); acc.y = fmaf(a.x, w0.y, acc.y);     \
  acc.z = fmaf(a.x, w0.z, acc.z); acc.w = fmaf(a.x, w0.w, acc.w);     \
  acc.x = fmaf(a.y, w1.x, acc.x); acc.y = fmaf(a.y, w1.y, acc.y);     \
  acc.z = fmaf(a.y, w1.z, acc.z); acc.w = fmaf(a.y, w1.w, acc.w);     \
  acc.x = fmaf(a.z, w2.x, acc.x); acc.y = fmaf(a.z, w2.y, acc.y);     \
  acc.z = fmaf(a.z, w2.z, acc.z); acc.w = fmaf(a.z, w2.w, acc.w);     \
  acc.x = fmaf(a.w, w3.x, acc.x); acc.y = fmaf(a.w, w3.y, acc.y);     \
  acc.z = fmaf(a.w, w3.z, acc.z); acc.w = fmaf(a.w, w3.w, acc.w);

// ---------------------------------------------------------------------------
// stage1 (v4-proven): blocks [0,512) h1 | [512,768) h2 | [768,1600) precompute
// ---------------------------------------------------------------------------
__global__ __launch_bounds__(256) void stage1(
    const float* __restrict__ encoding,  // [N][512]
    const float* __restrict__ mean,      // [N][1024]
    const float* __restrict__ enc_w1,    // [512][64]
    const float* __restrict__ pol_w1,    // [1024][32]
    const float* __restrict__ pol_b1,    // [32]
    const float* __restrict__ pol_w2,    // [32][32]
    const float* __restrict__ pol_b2,    // [32]
    const float* __restrict__ enc_w2,    // [64][1024]
    const float* __restrict__ pol_w3,    // [32][1024]
    const float* __restrict__ pol_b3,    // [1024]
    const float* __restrict__ comb_w,    // [2048][1024]
    const float* __restrict__ comb_b,    // [1024]
    float* __restrict__ h1h2,            // [N][96]
    float* __restrict__ fused)           // [97][1024] (pre-zeroed)
{
    __shared__ __attribute__((aligned(16))) float smem[64 * SPAD + 32 * 32]; // 13.3 KB
    const int t = threadIdx.x;
    const int bid = blockIdx.x;

    if (bid < 512) {
        // ---- h1: 32 rows x 64 cols, K=512 in 16 tiles of 32, reg-prefetch staging.
        float* sA = smem;                 // [32][SPAD]
        float* sW = smem + 32 * SPAD;     // [32][64]
        const long r0 = (long)bid * 32;
        const int tr = t & 15, rr = t >> 4;
        const int c0 = tr * 4;
        const int arow = t >> 3, aseg = t & 7;
        const float* aSrc = encoding + (r0 + arow) * IN_DIM + aseg * 4;

        float4 aR  = *(const float4*)(aSrc);
        float4 wR0 = *(const float4*)(enc_w1 + t * 4);
        float4 wR1 = *(const float4*)(enc_w1 + (256 + t) * 4);
        float4 acc0 = {0.f,0.f,0.f,0.f}, acc1 = {0.f,0.f,0.f,0.f};

        for (int kt = 0; kt < 16; ++kt) {
            __syncthreads();
            *(float4*)(sA + arow * SPAD + aseg * 4) = aR;
            *(float4*)(sW + t * 4) = wR0;
            *(float4*)(sW + (256 + t) * 4) = wR1;
            __syncthreads();
            if (kt < 15) {   // prefetch next tile while computing this one
                aR  = *(const float4*)(aSrc + (kt + 1) * 32);
                wR0 = *(const float4*)(enc_w1 + (kt + 1) * 2048 + t * 4);
                wR1 = *(const float4*)(enc_w1 + (kt + 1) * 2048 + (256 + t) * 4);
            }
            #pragma unroll
            for (int k4 = 0; k4 < 8; ++k4) {
                const float4 a0 = *(const float4*)(sA + (rr * 2 + 0) * SPAD + k4 * 4);
                const float4 a1 = *(const float4*)(sA + (rr * 2 + 1) * SPAD + k4 * 4);
                const float4 w0 = *(const float4*)(sW + (k4 * 4 + 0) * 64 + c0);
                const float4 w1 = *(const float4*)(sW + (k4 * 4 + 1) * 64 + c0);
                const float4 w2 = *(const float4*)(sW + (k4 * 4 + 2) * 64 + c0);
                const float4 w3 = *(const float4*)(sW + (k4 * 4 + 3) * 64 + c0);
                FMA4(acc0, a0, w0, w1, w2, w3);
                FMA4(acc1, a1, w0, w1, w2, w3);
            }
        }
        float4 o0, o1;
        o0.x = fmaxf(acc0.x, 0.f); o0.y = fmaxf(acc0.y, 0.f);
        o0.z = fmaxf(acc0.z, 0.f); o0.w = fmaxf(acc0.w, 0.f);
        o1.x = fmaxf(acc1.x, 0.f); o1.y = fmaxf(acc1.y, 0.f);
        o1.z = fmaxf(acc1.z, 0.f); o1.w = fmaxf(acc1.w, 0.f);
        *(float4*)(h1h2 + (r0 + rr * 2 + 0) * 96 + c0) = o0;
        *(float4*)(h1h2 + (r0 + rr * 2 + 1) * 96 + c0) = o1;
    } else if (bid < 768) {
        // ---- h2: 64 rows x 32 cols, K=1024 in 32 tiles of 32, then layer2 in-block.
        float* sA = smem;                 // [64][SPAD]
        float* sW = smem + 64 * SPAD;     // [32][32]
        const long r0 = (long)(bid - 512) * 64;
        const int tr = t & 7, rr = t >> 3;
        const int c0 = tr * 4;
        const int arow0 = t >> 3,        aseg = t & 7;
        const int arow1 = 32 + (t >> 3);
        const float* aSrc0 = mean + (r0 + arow0) * P + aseg * 4;
        const float* aSrc1 = mean + (r0 + arow1) * P + aseg * 4;

        float4 aR0 = *(const float4*)(aSrc0);
        float4 aR1 = *(const float4*)(aSrc1);
        float4 wR  = *(const float4*)(pol_w1 + t * 4);
        float4 acc0 = {0.f,0.f,0.f,0.f}, acc1 = {0.f,0.f,0.f,0.f};

        for (int kt = 0; kt < 32; ++kt) {
            __syncthreads();
            *(float4*)(sA + arow0 * SPAD + aseg * 4) = aR0;
            *(float4*)(sA + arow1 * SPAD + aseg * 4) = aR1;
            *(float4*)(sW + t * 4) = wR;
            __syncthreads();
            if (kt < 31) {
                aR0 = *(const float4*)(aSrc0 + (kt + 1) * 32);
                aR1 = *(const float4*)(aSrc1 + (kt + 1) * 32);
                wR  = *(const float4*)(pol_w1 + (kt + 1) * 1024 + t * 4);
            }
            #pragma unroll
            for (int k4 = 0; k4 < 8; ++k4) {
                const float4 a0 = *(const float4*)(sA + (rr * 2 + 0) * SPAD + k4 * 4);
                const float4 a1 = *(const float4*)(sA + (rr * 2 + 1) * SPAD + k4 * 4);
                const float4 w0 = *(const float4*)(sW + (k4 * 4 + 0) * 32 + c0);
                const float4 w1 = *(const float4*)(sW + (k4 * 4 + 1) * 32 + c0);
                const float4 w2 = *(const float4*)(sW + (k4 * 4 + 2) * 32 + c0);
                const float4 w3 = *(const float4*)(sW + (k4 * 4 + 3) * 32 + c0);
                FMA4(acc0, a0, w0, w1, w2, w3);
                FMA4(acc1, a1, w0, w1, w2, w3);
            }
        }
        // t1 = relu(acc+b1) -> sA; stage pol_w2 -> sW
        __syncthreads();
        {
            const float4 b1 = *(const float4*)(pol_b1 + c0);
            float4 t10, t11;
            t10.x = fmaxf(acc0.x + b1.x, 0.f); t10.y = fmaxf(acc0.y + b1.y, 0.f);
            t10.z = fmaxf(acc0.z + b1.z, 0.f); t10.w = fmaxf(acc0.w + b1.w, 0.f);
            t11.x = fmaxf(acc1.x + b1.x, 0.f); t11.y = fmaxf(acc1.y + b1.y, 0.f);
            t11.z = fmaxf(acc1.z + b1.z, 0.f); t11.w = fmaxf(acc1.w + b1.w, 0.f);
            *(float4*)(sA + (rr * 2 + 0) * SPAD + c0) = t10;
            *(float4*)(sA + (rr * 2 + 1) * SPAD + c0) = t11;
        }
        *(float4*)(sW + t * 4) = *(const float4*)(pol_w2 + t * 4);
        __syncthreads();

        float4 d0 = {0.f,0.f,0.f,0.f}, d1 = {0.f,0.f,0.f,0.f};
        #pragma unroll
        for (int k4 = 0; k4 < 8; ++k4) {
            const float4 a0 = *(const float4*)(sA + (rr * 2 + 0) * SPAD + k4 * 4);
            const float4 a1 = *(const float4*)(sA + (rr * 2 + 1) * SPAD + k4 * 4);
            const float4 w0 = *(const float4*)(sW + (k4 * 4 + 0) * 32 + c0);
            const float4 w1 = *(const float4*)(sW + (k4 * 4 + 1) * 32 + c0);
            const float4 w2 = *(const float4*)(sW + (k4 * 4 + 2) * 32 + c0);
            const float4 w3 = *(const float4*)(sW + (k4 * 4 + 3) * 32 + c0);
            FMA4(d0, a0, w0, w1, w2, w3);
            FMA4(d1, a1, w0, w1, w2, w3);
        }
        const float4 b2 = *(const float4*)(pol_b2 + c0);
        float4 o0, o1;
        o0.x = fmaxf(d0.x + b2.x, 0.f); o0.y = fmaxf(d0.y + b2.y, 0.f);
        o0.z = fmaxf(d0.z + b2.z, 0.f); o0.w = fmaxf(d0.w + b2.w, 0.f);
        o1.x = fmaxf(d1.x + b2.x, 0.f); o1.y = fmaxf(d1.y + b2.y, 0.f);
        o1.z = fmaxf(d1.z + b2.z, 0.f); o1.w = fmaxf(d1.w + b2.w, 0.f);
        *(float4*)(h1h2 + (r0 + rr * 2 + 0) * 96 + 64 + c0) = o0;
        *(float4*)(h1h2 + (r0 + rr * 2 + 1) * 96 + 64 + c0) = o1;
    } else {
        // ---- fused-weight precompute: pid -> (j-chunk, row-group, k-chunk of 64)
        const int pid = bid - 768;          // [0, 832)
        const int jc = pid & 3;
        const int rest = pid >> 2;          // [0, 208)
        const int by = rest % 13;
        const int kz = rest / 13;           // [0, 16)
        const int j = jc * 256 + t;

        const float* wsrc; int nr, kbase, outbase;
        if (by < 8)       { wsrc = enc_w2 + by * 8 * 1024;        nr = 8; kbase = 0;    outbase = by * 8; }
        else if (by < 12) { wsrc = pol_w3 + (by - 8) * 8 * 1024;  nr = 8; kbase = 1024; outbase = 64 + (by - 8) * 8; }
        else              { wsrc = pol_b3;                        nr = 1; kbase = 1024; outbase = 96; }

        float* s_w = smem;   // [8][64]
        for (int i = t; i < nr * 64; i += 256)
            s_w[i] = wsrc[(i >> 6) * 1024 + kz * 64 + (i & 63)];
        __syncthreads();

        float acc[8];
        #pragma unroll
        for (int r = 0; r < 8; ++r) acc[r] = 0.f;
        const float* cw = comb_w + ((size_t)kbase + kz * 64) * 1024 + j;
        #pragma unroll 4
        for (int k = 0; k < 64; ++k) {
            const float c = cw[(size_t)k * 1024];
            #pragma unroll
            for (int r = 0; r < 8; ++r) acc[r] = fmaf(s_w[r * 64 + k], c, acc[r]);
        }
        if (by == 12) {
            atomicAdd(&fused[96 * 1024 + j], acc[0] + (kz == 0 ? comb_b[j] : 0.f));
        } else {
            #pragma unroll
            for (int r = 0; r < 8; ++r) atomicAdd(&fused[(outbase + r) * 1024 + j], acc[r]);
        }
    }
}

// ---------------------------------------------------------------------------
// logits + epilogue, scalar-broadcast edition. Block = 8 rows x 1024 cols
// (2048 blocks); thread = 8 rows x 4 contiguous cols. h read via WAVE-UNIFORM
// global loads -> s_load_dwordx4 on the SMEM pipe; the FMA's multiplicand is
// the SGPR operand. No LDS in the GEMM; w (fused cols) register-dbuf from L2.
// ---------------------------------------------------------------------------
__global__ __launch_bounds__(256) void logits_ep(
    const float* __restrict__ h1h2,    // [N][96]
    const float* __restrict__ fused,   // [97][1024]
    const float* __restrict__ eps,     // [N][1024]
    float* __restrict__ out_sample,    // [N][1024]
    float* __restrict__ out_logprob,   // [N]
    float* __restrict__ out_entropy)   // [N]
{
    __shared__ float s_red[8][4];
    const int t = threadIdx.x;
    const long r0 = (long)blockIdx.x * 8;
    const float* hb = h1h2 + r0 * 96;   // block-uniform base

    const int j0 = t * 4;
    const float* fj = fused + j0;

    float4 acc[8];
    {
        const float4 b = *(const float4*)(fj + 96 * 1024);
        #pragma unroll
        for (int r = 0; r < 8; ++r) acc[r] = b;
    }

    float4 wc0 = *(const float4*)(fj);
    float4 wc1 = *(const float4*)(fj + 1024);
    float4 wc2 = *(const float4*)(fj + 2048);
    float4 wc3 = *(const float4*)(fj + 3072);

    for (int k4 = 0; k4 < 24; ++k4) {
        const int kn = (k4 < 23) ? (k4 + 1) * 4 : 92;   // last-iter dummy prefetch
        const float* fn = fj + (size_t)kn * 1024;
        const float4 wn0 = *(const float4*)(fn);
        const float4 wn1 = *(const float4*)(fn + 1024);
        const float4 wn2 = *(const float4*)(fn + 2048);
        const float4 wn3 = *(const float4*)(fn + 3072);
        #pragma unroll
        for (int r = 0; r < 8; ++r) {
            // uniform address (hb block-uniform, r/k4 wave-uniform) -> s_load_dwordx4
            const float4 h = *(const float4*)(hb + r * 96 + k4 * 4);
            FMA4(acc[r], h, wc0, wc1, wc2, wc3);
        }
        wc0 = wn0; wc1 = wn1; wc2 = wn2; wc3 = wn3;
    }

    float sq[8];
    const float* ep = eps + r0 * P + j0;
    float* sp = out_sample + r0 * P + j0;
    #pragma unroll
    for (int r = 0; r < 8; ++r) {
        const float m0 = 1.f / (1.f + __expf(-acc[r].x));
        const float m1 = 1.f / (1.f + __expf(-acc[r].y));
        const float m2 = 1.f / (1.f + __expf(-acc[r].z));
        const float m3 = 1.f / (1.f + __expf(-acc[r].w));
        const float4 e = *(const float4*)(ep + r * P);
        const float s0 = fminf(fmaxf(fmaf(0.22360679774997896f, e.x, m0), 0.f), 1.f);
        const float s1 = fminf(fmaxf(fmaf(0.22360679774997896f, e.y, m1), 0.f), 1.f);
        const float s2 = fminf(fmaxf(fmaf(0.22360679774997896f, e.z, m2), 0.f), 1.f);
        const float s3 = fminf(fmaxf(fmaf(0.22360679774997896f, e.w, m3), 0.f), 1.f);
        *(float4*)(sp + r * P) = make_float4(s0, s1, s2, s3);
        const float d0 = s0 - m0, d1 = s1 - m1, d2 = s2 - m2, d3 = s3 - m3;
        sq[r] = fmaf(d0, d0, fmaf(d1, d1, fmaf(d2, d2, d3 * d3)));
    }
    #pragma unroll
    for (int r = 0; r < 8; ++r) {
        float v = sq[r];
        v += __shfl_xor(v, 1);
        v += __shfl_xor(v, 2);
        v += __shfl_xor(v, 4);
        v += __shfl_xor(v, 8);
        v += __shfl_xor(v, 16);
        v += __shfl_xor(v, 32);
        if ((t & 63) == 0) s_red[r][t >> 6] = v;
    }
    __syncthreads();
    if (t < 8) {
        const float v = s_red[t][0] + s_red[t][1] + s_red[t][2] + s_red[t][3];
        out_logprob[r0 + t] = fmaf(-10.f, v, 592.8218660580586f);
        out_entropy[r0 + t] = -80.82186605805855f;
    }
}

extern "C" void kernel_launch(void* const* d_in, const int* in_sizes, int n_in,
                              void* d_out, int out_size, void* d_ws, size_t ws_size,
                              hipStream_t stream) {
    const float* encoding = (const float*)d_in[0];
    const float* mean     = (const float*)d_in[1];
    const float* enc_w1   = (const float*)d_in[2];
    const float* enc_w2   = (const float*)d_in[3];
    const float* pol_w1   = (const float*)d_in[4];
    const float* pol_b1   = (const float*)d_in[5];
    const float* pol_w2   = (const float*)d_in[6];
    const float* pol_b2   = (const float*)d_in[7];
    const float* pol_w3   = (const float*)d_in[8];
    const float* pol_b3   = (const float*)d_in[9];
    const float* comb_w   = (const float*)d_in[10];
    const float* comb_b   = (const float*)d_in[11];
    const float* eps      = (const float*)d_in[12];

    float* fused = (float*)d_ws;                          // 97*1024 floats
    float* h1h2  = fused + 97 * 1024;                     // 16384*96 floats
    float* out_sample  = (float*)d_out;
    float* out_logprob = out_sample + (size_t)N_CLIENTS * P;
    float* out_entropy = out_logprob + N_CLIENTS;

    (void)hipMemsetAsync(fused, 0, 97 * 1024 * sizeof(float), stream);

    stage1<<<1600, 256, 0, stream>>>(encoding, mean, enc_w1, pol_w1, pol_b1,
                                     pol_w2, pol_b2, enc_w2, pol_w3, pol_b3,
                                     comb_w, comb_b, h1h2, fused);

    logits_ep<<<N_CLIENTS / 8, 256, 0, stream>>>(
        h1h2, fused, eps, out_sample, out_logprob, out_entropy);
}